// Round 16
// baseline (164.624 us; speedup 1.0000x reference)
//
#include <hip/hip_runtime.h>
#include <hip/hip_bf16.h>

// Problem constants
#define BATCH 8
#define SEQ   1024
#define CDIM  768
#define HEADS 12
#define HD    64

// Logits kept in t' = log2(e) * (s - o) units (native exp2/log2).
// Coarse histogram: 2048 bins over t' in [-24, 0]; built from a stratified
// 1/8 subsample (kT=0 rows of even chunks) cached as bf16 during sweep 1.
#define NB1    2048
#define TMIN2  (-24.0f)
#define W2     (24.0f / (float)NB1)
#define INV_W2 ((float)NB1 / 24.0f)
#define HLSTR  (NB1 + 8)              // LDS copy stride: +8 banks
#define K_SUB  314573u                // int(12M*0.2)/8
#define QSCALE 0.18033688011112042f   // 0.125 * log2(e)

typedef __attribute__((ext_vector_type(8)))  short bf16x8;
typedef __attribute__((ext_vector_type(4)))  short bf16x4;
typedef __attribute__((ext_vector_type(4)))  float f32x4;
typedef __attribute__((ext_vector_type(16))) float f32x16;
typedef __attribute__((ext_vector_type(4)))  unsigned u32x4;
typedef __attribute__((ext_vector_type(2)))  unsigned u32x2;

#define MFMA16(a, b, c) __builtin_amdgcn_mfma_f32_16x16x32_bf16(a, b, c, 0, 0, 0)
#define MFMA32(a, b, c) __builtin_amdgcn_mfma_f32_32x32x16_bf16(a, b, c, 0, 0, 0)
#define EXP2(x) __builtin_amdgcn_exp2f(x)
#define LOG2(x) __builtin_amdgcn_logf(x)

// HW packed f32->bf16 (RNE): src0 -> lo16, src1 -> hi16.
__device__ inline unsigned cvtpk(float lo, float hi) {
    unsigned r;
    asm("v_cvt_pk_bf16_f32 %0, %1, %2" : "=v"(r) : "v"(lo), "v"(hi));
    return r;
}

// ---------------------------------------------------------------------------
// Prep: W transposes only (x conversion is fused into qkv's staging).
// Blocks [0,432) transpose W_qkv; [432,576) transpose W_proj.
// Blocks [0,64) additionally zero the 64 KB global histogram (replaces the
// hipMemsetAsync dispatch).
// ---------------------------------------------------------------------------
__global__ __launch_bounds__(256) void prep_all(const float* __restrict__ Wq,
                                                const float* __restrict__ Wp,
                                                short* __restrict__ wqt,
                                                short* __restrict__ wpt,
                                                unsigned* __restrict__ hist) {
    __shared__ float ls[64][68];
    int bid = blockIdx.x, tid = threadIdx.x;
    if (bid < 64) hist[bid * 256 + tid] = 0u;   // 64*256 = 16384 = 8*NB1
    const float* in;
    short* out;
    int C, t;
    if (bid < 432) { t = bid; in = Wq; out = wqt; C = 2304; }
    else           { t = bid - 432; in = Wp; out = wpt; C = 768; }
    int r0 = (t % 12) * 64, c0 = (t / 12) * 64;
#pragma unroll
    for (int it = 0; it < 4; ++it) {
        int rr = it * 16 + (tid >> 4);
        int cc = (tid & 15) * 4;
        float4 d = *reinterpret_cast<const float4*>(&in[(size_t)(r0 + rr) * C + c0 + cc]);
        ls[rr][cc + 0] = d.x; ls[rr][cc + 1] = d.y; ls[rr][cc + 2] = d.z; ls[rr][cc + 3] = d.w;
    }
    __syncthreads();
#pragma unroll
    for (int it = 0; it < 2; ++it) {
        int orow = it * 32 + (tid >> 3);
        int oc = (tid & 7) * 8;
        u32x4 w = {cvtpk(ls[oc + 0][orow], ls[oc + 1][orow]),
                   cvtpk(ls[oc + 2][orow], ls[oc + 3][orow]),
                   cvtpk(ls[oc + 4][orow], ls[oc + 5][orow]),
                   cvtpk(ls[oc + 6][orow], ls[oc + 7][orow])};
        *reinterpret_cast<u32x4*>(&out[(size_t)(c0 + orow) * 768 + r0 + oc]) = w;
    }
}

// ---------------------------------------------------------------------------
// Kernel 1: qkv = x @ Wqt^T via MFMA with T14 split staging.  A-side reads
// fp32 x DIRECTLY and packs to bf16 (cvtpk RNE, bitwise-identical to the
// old convert_x path) during staging -- the xb pre-pass is gone.
// Writes bf16 q (x QSCALE), k [bh][n][d], V transposed vt [bh][d][n].
// ---------------------------------------------------------------------------
__global__ __launch_bounds__(256) void qkv_mfma(const float* __restrict__ X,
                                                const short* __restrict__ Bt,
                                                __hip_bfloat16* __restrict__ q,
                                                __hip_bfloat16* __restrict__ k,
                                                __hip_bfloat16* __restrict__ vt) {
    const int K = 768;
    __shared__ short As[128 * 64];
    __shared__ short Bs[128 * 64];
    int tM = blockIdx.x * 128, tN = blockIdx.y * 128;
    int tid = threadIdx.x, wave = tid >> 6, lane = tid & 63, lg = lane >> 4, lc = lane & 15;
    int wr = wave >> 1, wc = wave & 1;
    int srow = tid >> 3, scol = (tid & 7) * 8;
    f32x4 acc[4][4] = {};

    u32x4 sa[4];
    bf16x8 sb[4];
#pragma unroll
    for (int j = 0; j < 4; ++j) {
        int r = j * 32 + srow;
        float4 xa = *reinterpret_cast<const float4*>(&X[(size_t)(tM + r) * K + scol]);
        float4 xb2 = *reinterpret_cast<const float4*>(&X[(size_t)(tM + r) * K + scol + 4]);
        sa[j] = u32x4{cvtpk(xa.x, xa.y), cvtpk(xa.z, xa.w), cvtpk(xb2.x, xb2.y), cvtpk(xb2.z, xb2.w)};
        sb[j] = *(const bf16x8*)&Bt[(size_t)(tN + r) * K + scol];
    }
#pragma unroll
    for (int j = 0; j < 4; ++j) {
        int r = j * 32 + srow;
        int sw = scol ^ ((r & 7) << 3);
        *(u32x4*)&As[r * 64 + sw] = sa[j];
        *(bf16x8*)&Bs[r * 64 + sw] = sb[j];
    }
    __syncthreads();

    for (int kc = 0; kc < K; kc += 64) {
        if (kc + 64 < K) {
#pragma unroll
            for (int j = 0; j < 4; ++j) {
                int r = j * 32 + srow;
                float4 xa = *reinterpret_cast<const float4*>(&X[(size_t)(tM + r) * K + kc + 64 + scol]);
                float4 xb2 = *reinterpret_cast<const float4*>(&X[(size_t)(tM + r) * K + kc + 64 + scol + 4]);
                sa[j] = u32x4{cvtpk(xa.x, xa.y), cvtpk(xa.z, xa.w), cvtpk(xb2.x, xb2.y), cvtpk(xb2.z, xb2.w)};
                sb[j] = *(const bf16x8*)&Bt[(size_t)(tN + r) * K + kc + 64 + scol];
            }
        }
        bf16x8 af[4][2], bfr[4][2];
#pragma unroll
        for (int m4 = 0; m4 < 4; ++m4) {
            int r = wr * 64 + m4 * 16 + lc;
            int sw = (r & 7) << 3;
            af[m4][0] = *(bf16x8*)&As[r * 64 + ((lg * 8) ^ sw)];
            af[m4][1] = *(bf16x8*)&As[r * 64 + ((32 + lg * 8) ^ sw)];
        }
#pragma unroll
        for (int n4 = 0; n4 < 4; ++n4) {
            int r = wc * 64 + n4 * 16 + lc;
            int sw = (r & 7) << 3;
            bfr[n4][0] = *(bf16x8*)&Bs[r * 64 + ((lg * 8) ^ sw)];
            bfr[n4][1] = *(bf16x8*)&Bs[r * 64 + ((32 + lg * 8) ^ sw)];
        }
#pragma unroll
        for (int m4 = 0; m4 < 4; ++m4)
#pragma unroll
            for (int n4 = 0; n4 < 4; ++n4) {
                acc[m4][n4] = MFMA16(af[m4][0], bfr[n4][0], acc[m4][n4]);
                acc[m4][n4] = MFMA16(af[m4][1], bfr[n4][1], acc[m4][n4]);
            }
        __syncthreads();
        if (kc + 64 < K) {
#pragma unroll
            for (int j = 0; j < 4; ++j) {
                int r = j * 32 + srow;
                int sw = scol ^ ((r & 7) << 3);
                *(u32x4*)&As[r * 64 + sw] = sa[j];
                *(bf16x8*)&Bs[r * 64 + sw] = sb[j];
            }
            __syncthreads();
        }
    }
    int three = tN / 768;
    int cbase = tN - three * 768 + wc * 64;
    if (three == 2) {
#pragma unroll
        for (int m4 = 0; m4 < 4; ++m4) {
            int row0 = tM + wr * 64 + m4 * 16 + lg * 4;
            int b = row0 >> 10, n0 = row0 & 1023;
#pragma unroll
            for (int n4 = 0; n4 < 4; ++n4) {
                int cw = cbase + n4 * 16 + lc;
                int h = cw >> 6, d = cw & 63;
                u32x2 w = {cvtpk(acc[m4][n4][0], acc[m4][n4][1]),
                           cvtpk(acc[m4][n4][2], acc[m4][n4][3])};
                *reinterpret_cast<u32x2*>(
                    &vt[(((size_t)(b * HEADS + h) * 64 + d) << 10) + n0]) = w;
            }
        }
    } else {
        __hip_bfloat16* dst = (three == 0) ? q : k;
#pragma unroll
        for (int m4 = 0; m4 < 4; ++m4)
#pragma unroll
            for (int n4 = 0; n4 < 4; ++n4) {
                int cw = cbase + n4 * 16 + lc;
                int h = cw >> 6, d = cw & 63;
#pragma unroll
                for (int r = 0; r < 4; r += 2) {
                    int row = tM + wr * 64 + m4 * 16 + lg * 4 + r;
                    int b = row >> 10, n = row & 1023;
                    float v0 = acc[m4][n4][r], v1 = acc[m4][n4][r + 1];
                    if (three == 0) { v0 *= QSCALE; v1 *= QSCALE; }
                    unsigned w = cvtpk(v0, v1);
                    size_t base = (((size_t)(b * HEADS + h) << 10) + n) * HD + d;
                    *(unsigned short*)&dst[base] = (unsigned short)w;
                    *(unsigned short*)&dst[base + HD] = (unsigned short)(w >> 16);
                }
            }
    }
}

// ---------------------------------------------------------------------------
// Kernel 2: single-sweep stats + T1 XCD swizzle.
// lsum = sum exp2(s') -> o = log2(lsum); 1/8 stratified sample cached in
// regs during the sweep, binned after o.  Grid = 768 (12 heads per XCD).
// ---------------------------------------------------------------------------
__global__ __launch_bounds__(256) void stats_mfma(const short* __restrict__ q,
                                                  const short* __restrict__ k,
                                                  float* __restrict__ orow,
                                                  unsigned* __restrict__ hist) {
    __shared__ short kls[8192];             // [128 k][64 d], XOR-swizzled
    __shared__ unsigned hl[2 * HLSTR];
    int bid = (blockIdx.x & 7) * 96 + (blockIdx.x >> 3);   // XCD-contiguous heads
    int grp = bid & 7;
    int bh = bid >> 3;
    int b = bh / HEADS;
    int tid = threadIdx.x, wave = tid >> 6, lane = tid & 63;
    int ql = lane & 31, h = lane >> 5;
    const short* kbase = k + (size_t)bh * SEQ * HD;
    int qrow0 = grp * 128 + wave * 32;
    const short* qbase = q + ((size_t)bh * SEQ + qrow0) * HD;
    bf16x8 qf[4];
#pragma unroll
    for (int f = 0; f < 4; ++f)
        qf[f] = *(const bf16x8*)&qbase[ql * 64 + f * 16 + h * 8];

    for (int i = tid; i < 2 * HLSTR; i += 256) hl[i] = 0;

    int srow = tid >> 3, scol = (tid & 7) * 8;
    unsigned scache[4][8];   // even chunks' kT=0 S-values, packed bf16

    bf16x8 st[4];
#pragma unroll
    for (int j = 0; j < 4; ++j)
        st[j] = *(const bf16x8*)&kbase[(size_t)(j * 32 + srow) * 64 + scol];
#pragma unroll
    for (int j = 0; j < 4; ++j) {
        int r = j * 32 + srow;
        *(bf16x8*)&kls[r * 64 + (scol ^ ((r & 7) << 3))] = st[j];
    }
    __syncthreads();
    float lsum = 0.f;
#pragma unroll
    for (int c = 0; c < 8; ++c) {
        if (c < 7) {
#pragma unroll
            for (int j = 0; j < 4; ++j)
                st[j] = *(const bf16x8*)&kbase[(size_t)((c + 1) * 128 + j * 32 + srow) * 64 + scol];
        }
#pragma unroll
        for (int kT = 0; kT < 4; ++kT) {
            f32x16 acc = {};
#pragma unroll
            for (int f = 0; f < 4; ++f) {
                int krow = kT * 32 + ql;
                bf16x8 af = *(bf16x8*)&kls[krow * 64 + ((f * 16 + h * 8) ^ ((krow & 7) << 3))];
                acc = MFMA32(af, qf[f], acc);
            }
            if (kT == 0 && (c & 1) == 0) {
#pragma unroll
                for (int i = 0; i < 8; ++i)
                    scache[c >> 1][i] = cvtpk(acc[2 * i], acc[2 * i + 1]);
            }
            float s = 0.f;
#pragma unroll
            for (int r = 0; r < 16; ++r) s += EXP2(acc[r]);
            lsum += s;
        }
        __syncthreads();
        if (c < 7) {
#pragma unroll
            for (int j = 0; j < 4; ++j) {
                int r = j * 32 + srow;
                *(bf16x8*)&kls[r * 64 + (scol ^ ((r & 7) << 3))] = st[j];
            }
            __syncthreads();
        }
    }
    lsum += __shfl_xor(lsum, 32, 64);
    float o = LOG2(lsum);
    if (h == 0) orow[(size_t)bh * SEQ + qrow0 + ql] = o;

    // bin the cached 1/8 sample
    unsigned coff = (lane & 1) * HLSTR;
#pragma unroll
    for (int cc = 0; cc < 4; ++cc)
#pragma unroll
        for (int i = 0; i < 8; ++i) {
            unsigned w = scache[cc][i];
            float s0 = __builtin_bit_cast(float, w << 16);
            float s1 = __builtin_bit_cast(float, w & 0xffff0000u);
            int b0 = (int)((s0 - o) * INV_W2 + (float)NB1);
            int b1 = (int)((s1 - o) * INV_W2 + (float)NB1);
            b0 = b0 < 0 ? 0 : (b0 > NB1 - 1 ? NB1 - 1 : b0);
            b1 = b1 < 0 ? 0 : (b1 > NB1 - 1 ? NB1 - 1 : b1);
            atomicAdd(&hl[coff + b0], 1u);
            atomicAdd(&hl[coff + b1], 1u);
        }
    __syncthreads();
    unsigned* hb = hist + (size_t)b * NB1;
    for (int i = tid; i < NB1; i += 256) {
        unsigned s = hl[i] + hl[HLSTR + i];
        if (s) atomicAdd(&hb[i], s);
    }
}

// ---------------------------------------------------------------------------
// Kernel 3: per-batch threshold (subsampled counts: K_SUB)
// ---------------------------------------------------------------------------
__global__ __launch_bounds__(256) void find_thr(const unsigned* __restrict__ hist,
                                                float* __restrict__ thr) {
    __shared__ unsigned cs[256];
    int b = blockIdx.x, tid = threadIdx.x;
    const unsigned* hb = hist + (size_t)b * NB1;
    unsigned s = 0;
#pragma unroll
    for (int i = 0; i < 8; ++i) s += hb[tid * 8 + i];
    cs[tid] = s;
    __syncthreads();
    unsigned suf = 0;
    for (int j = tid; j < 256; ++j) suf += cs[j];
    unsigned above = suf - cs[tid];
    if (suf >= K_SUB && above < K_SUB) {
        unsigned acc = above;
        for (int bb = 7; bb >= 0; --bb) {
            acc += hb[tid * 8 + bb];
            if (acc >= K_SUB) {
                thr[b] = TMIN2 + (float)(tid * 8 + bb) * W2;
                break;
            }
        }
    }
}

// ---------------------------------------------------------------------------
// Kernel 4: k-split PV + T1 XCD swizzle.  Block = 64 q-rows; 4 waves =
// {rowhalf} x {khalf}.  Grid = 1536 (12 heads per XCD; K/V L2-resident).
// ---------------------------------------------------------------------------
__global__ __launch_bounds__(256) void pv_mfma(const short* __restrict__ q,
                                               const short* __restrict__ k,
                                               const short* __restrict__ vt,
                                               const float* __restrict__ orow,
                                               const float* __restrict__ thr,
                                               __hip_bfloat16* __restrict__ aout) {
    __shared__ __align__(16) char smem[32768];
    short* klsA = (short*)smem;
    short* klsB = (short*)(smem + 8192);
    short* vlsA = (short*)(smem + 16384);
    short* vlsB = (short*)(smem + 24576);
    float* comb = (float*)smem;

    int bid = (blockIdx.x & 7) * 192 + (blockIdx.x >> 3);   // XCD-contiguous heads
    int grp = bid & 15;
    int bh = bid >> 4;
    int b = bh / HEADS, hh = bh % HEADS;
    int tid = threadIdx.x, wave = tid >> 6, lane = tid & 63;
    int ql = lane & 31, h = lane >> 5;
    int rh = wave & 1;
    int kh = wave >> 1;
    const short* kbase = k + (size_t)bh * SEQ * HD;
    const short* vtb = vt + (size_t)bh * HD * SEQ;
    int qrow0 = grp * 64 + rh * 32;
    const short* qbase = q + ((size_t)bh * SEQ + qrow0) * HD;
    bf16x8 qf[4];
#pragma unroll
    for (int f = 0; f < 4; ++f)
        qf[f] = *(const bf16x8*)&qbase[ql * 64 + f * 16 + h * 8];
    float o = orow[(size_t)bh * SEQ + qrow0 + ql];
    float tt = thr[b];
    f32x16 oacc[2] = {};
    f32x16 minus_o;
#pragma unroll
    for (int r = 0; r < 16; ++r) minus_o[r] = -o;

    short* kls = kh ? klsB : klsA;
    short* vls = kh ? vlsB : vlsA;

    int sp = tid >> 7;
    int tl = tid & 127;
    int srow = tl >> 3, scol = (tl & 7) * 8;
    short* skls = sp ? klsB : klsA;
    short* svls = sp ? vlsB : vlsA;

    bf16x8 sk[4], sv[4];
    int cc0 = sp * 8;
#pragma unroll
    for (int j = 0; j < 4; ++j) {
        int r = j * 16 + srow;
        sk[j] = *(const bf16x8*)&kbase[(size_t)(cc0 * 64 + r) * 64 + scol];
        sv[j] = *(const bf16x8*)&vtb[((size_t)r << 10) + cc0 * 64 + scol];
    }
#pragma unroll
    for (int j = 0; j < 4; ++j) {
        int r = j * 16 + srow;
        *(bf16x8*)&skls[r * 64 + (scol ^ ((r & 7) << 3))] = sk[j];
        *(bf16x8*)&svls[r * 64 + (scol ^ ((r & 7) << 3))] = sv[j];
    }
    __syncthreads();

    for (int c = 0; c < 8; ++c) {
        if (c < 7) {
            int cc = sp * 8 + c + 1;
#pragma unroll
            for (int j = 0; j < 4; ++j) {
                int r = j * 16 + srow;
                sk[j] = *(const bf16x8*)&kbase[(size_t)(cc * 64 + r) * 64 + scol];
                sv[j] = *(const bf16x8*)&vtb[((size_t)r << 10) + cc * 64 + scol];
            }
        }
#pragma unroll
        for (int kT = 0; kT < 2; ++kT) {
            f32x16 acc = minus_o;
#pragma unroll
            for (int f = 0; f < 4; ++f) {
                int krow = kT * 32 + ql;
                bf16x8 af = *(bf16x8*)&kls[krow * 64 + ((f * 16 + h * 8) ^ ((krow & 7) << 3))];
                acc = MFMA32(af, qf[f], acc);
            }
            float p[16];
#pragma unroll
            for (int r = 0; r < 16; ++r)
                p[r] = (acc[r] >= tt) ? EXP2(acc[r]) : 0.f;
            unsigned c8[8];
#pragma unroll
            for (int i = 0; i < 8; ++i) c8[i] = cvtpk(p[2 * i], p[2 * i + 1]);
#pragma unroll
            for (int s = 0; s < 2; ++s) {
                unsigned a1 = c8[4 * s],     b1 = c8[4 * s + 2];
                unsigned a2 = c8[4 * s + 1], b2 = c8[4 * s + 3];
                asm("v_permlane32_swap_b32 %0, %1" : "+v"(a1), "+v"(b1));
                asm("v_permlane32_swap_b32 %0, %1" : "+v"(a2), "+v"(b2));
                u32x4 W = {a1, a2, b1, b2};
                bf16x8 pa = __builtin_bit_cast(bf16x8, W);
#pragma unroll
                for (int dt = 0; dt < 2; ++dt) {
                    int vrow = dt * 32 + ql;
                    int vcol = (kT * 32 + s * 16 + h * 8) ^ ((vrow & 7) << 3);
                    bf16x8 vf = *(bf16x8*)&vls[vrow * 64 + vcol];
                    oacc[dt] = MFMA32(pa, vf, oacc[dt]);
                }
            }
        }
        __syncthreads();
        if (c < 7) {
#pragma unroll
            for (int j = 0; j < 4; ++j) {
                int r = j * 16 + srow;
                *(bf16x8*)&skls[r * 64 + (scol ^ ((r & 7) << 3))] = sk[j];
                *(bf16x8*)&svls[r * 64 + (scol ^ ((r & 7) << 3))] = sv[j];
            }
            __syncthreads();
        }
    }

    if (kh == 1) {
#pragma unroll
        for (int dt = 0; dt < 2; ++dt)
#pragma unroll
            for (int r = 0; r < 16; ++r) {
                int crow = (r & 3) + 8 * (r >> 2) + 4 * h;
                comb[(rh * 32 + crow) * 65 + dt * 32 + ql] = oacc[dt][r];
            }
    }
    __syncthreads();
    if (kh == 1) return;
#pragma unroll
    for (int dt = 0; dt < 2; ++dt)
#pragma unroll
        for (int r = 0; r < 16; ++r) {
            int crow = (r & 3) + 8 * (r >> 2) + 4 * h;
            oacc[dt][r] += comb[(rh * 32 + crow) * 65 + dt * 32 + ql];
        }
#pragma unroll
    for (int dt = 0; dt < 2; ++dt)
#pragma unroll
        for (int r = 0; r < 16; r += 2) {
            int qr0 = qrow0 + (r & 3) + 8 * (r >> 2) + 4 * h;
            int qr1 = qrow0 + ((r + 1) & 3) + 8 * ((r + 1) >> 2) + 4 * h;
            unsigned w = cvtpk(oacc[dt][r], oacc[dt][r + 1]);
            *(unsigned short*)&aout[((size_t)b * SEQ + qr0) * CDIM + hh * 64 + dt * 32 + ql] =
                (unsigned short)w;
            *(unsigned short*)&aout[((size_t)b * SEQ + qr1) * CDIM + hh * 64 + dt * 32 + ql] =
                (unsigned short)(w >> 16);
        }
}

// ---------------------------------------------------------------------------
// Kernel 5: out = aoutb @ Wpt^T + b_proj + origin (MFMA, fp32 epilogue),
// T14 split staging.
// ---------------------------------------------------------------------------
__global__ __launch_bounds__(256) void proj_mfma(const short* __restrict__ A,
                                                 const short* __restrict__ Bt,
                                                 const float* __restrict__ bias,
                                                 const float* __restrict__ origin,
                                                 float* __restrict__ out) {
    const int K = 768, NN = 768;
    __shared__ short As[128 * 64];
    __shared__ short Bs[128 * 64];
    int tM = blockIdx.x * 128, tN = blockIdx.y * 128;
    int tid = threadIdx.x, wave = tid >> 6, lane = tid & 63, lg = lane >> 4, lc = lane & 15;
    int wr = wave >> 1, wc = wave & 1;
    int srow = tid >> 3, scol = (tid & 7) * 8;
    f32x4 acc[4][4] = {};

    bf16x8 sa[4], sb[4];
#pragma unroll
    for (int j = 0; j < 4; ++j) {
        int r = j * 32 + srow;
        sa[j] = *(const bf16x8*)&A[(size_t)(tM + r) * K + scol];
        sb[j] = *(const bf16x8*)&Bt[(size_t)(tN + r) * K + scol];
    }
#pragma unroll
    for (int j = 0; j < 4; ++j) {
        int r = j * 32 + srow;
        int sw = scol ^ ((r & 7) << 3);
        *(bf16x8*)&As[r * 64 + sw] = sa[j];
        *(bf16x8*)&Bs[r * 64 + sw] = sb[j];
    }
    __syncthreads();

    for (int kc = 0; kc < K; kc += 64) {
        if (kc + 64 < K) {
#pragma unroll
            for (int j = 0; j < 4; ++j) {
                int r = j * 32 + srow;
                sa[j] = *(const bf16x8*)&A[(size_t)(tM + r) * K + kc + 64 + scol];
                sb[j] = *(const bf16x8*)&Bt[(size_t)(tN + r) * K + kc + 64 + scol];
            }
        }
        bf16x8 af[4][2], bfr[4][2];
#pragma unroll
        for (int m4 = 0; m4 < 4; ++m4) {
            int r = wr * 64 + m4 * 16 + lc;
            int sw = (r & 7) << 3;
            af[m4][0] = *(bf16x8*)&As[r * 64 + ((lg * 8) ^ sw)];
            af[m4][1] = *(bf16x8*)&As[r * 64 + ((32 + lg * 8) ^ sw)];
        }
#pragma unroll
        for (int n4 = 0; n4 < 4; ++n4) {
            int r = wc * 64 + n4 * 16 + lc;
            int sw = (r & 7) << 3;
            bfr[n4][0] = *(bf16x8*)&Bs[r * 64 + ((lg * 8) ^ sw)];
            bfr[n4][1] = *(bf16x8*)&Bs[r * 64 + ((32 + lg * 8) ^ sw)];
        }
#pragma unroll
        for (int m4 = 0; m4 < 4; ++m4)
#pragma unroll
            for (int n4 = 0; n4 < 4; ++n4) {
                acc[m4][n4] = MFMA16(af[m4][0], bfr[n4][0], acc[m4][n4]);
                acc[m4][n4] = MFMA16(af[m4][1], bfr[n4][1], acc[m4][n4]);
            }
        __syncthreads();
        if (kc + 64 < K) {
#pragma unroll
            for (int j = 0; j < 4; ++j) {
                int r = j * 32 + srow;
                int sw = scol ^ ((r & 7) << 3);
                *(bf16x8*)&As[r * 64 + sw] = sa[j];
                *(bf16x8*)&Bs[r * 64 + sw] = sb[j];
            }
            __syncthreads();
        }
    }
#pragma unroll
    for (int m4 = 0; m4 < 4; ++m4)
#pragma unroll
        for (int n4 = 0; n4 < 4; ++n4)
#pragma unroll
            for (int r = 0; r < 4; ++r) {
                int row = tM + wr * 64 + m4 * 16 + lg * 4 + r;
                int col = tN + wc * 64 + n4 * 16 + lc;
                out[(size_t)row * NN + col] = acc[m4][n4][r] + bias[col] + origin[(size_t)row * NN + col];
            }
}

// ---------------------------------------------------------------------------
extern "C" void kernel_launch(void* const* d_in, const int* in_sizes, int n_in,
                              void* d_out, int out_size, void* d_ws, size_t ws_size,
                              hipStream_t stream) {
    const float* x      = (const float*)d_in[0];
    const float* origin = (const float*)d_in[1];
    const float* W_qkv  = (const float*)d_in[2];
    const float* W_proj = (const float*)d_in[3];
    const float* b_proj = (const float*)d_in[4];
    float* out = (float*)d_out;
    char* ws = (char*)d_ws;

    const size_t QKV_ELEMS = (size_t)BATCH * HEADS * SEQ * HD;   // 6291456
    size_t off = 0;
    short* wqt = (short*)(ws + off); off += (size_t)2304 * 768 * 2;
    short* wpt = (short*)(ws + off); off += (size_t)768 * 768 * 2;
    short* q   = (short*)(ws + off); off += QKV_ELEMS * 2;
    short* k   = (short*)(ws + off); off += QKV_ELEMS * 2;
    short* vt  = (short*)(ws + off); off += QKV_ELEMS * 2;
    short* aoutb = (short*)(ws + off); off += QKV_ELEMS * 2;
    float* orow = (float*)(ws + off); off += (size_t)BATCH * HEADS * SEQ * 4;
    unsigned* hist = (unsigned*)(ws + off); off += (size_t)BATCH * NB1 * 4;
    float* thr = (float*)(ws + off); off += 8 * 4;

    prep_all<<<dim3(576), 256, 0, stream>>>(W_qkv, W_proj, wqt, wpt, hist);
    qkv_mfma<<<dim3(64, 18), 256, 0, stream>>>(x, wqt,
                                               (__hip_bfloat16*)q, (__hip_bfloat16*)k, (__hip_bfloat16*)vt);
    stats_mfma<<<dim3(BATCH * HEADS * 8), 256, 0, stream>>>(q, k, orow, hist);
    find_thr<<<dim3(BATCH), 256, 0, stream>>>(hist, thr);
    pv_mfma<<<dim3(BATCH * HEADS * 16), 256, 0, stream>>>(q, k, vt, orow, thr,
                                                          (__hip_bfloat16*)aoutb);
    proj_mfma<<<dim3(64, 6), 256, 0, stream>>>(aoutb, wpt, b_proj, origin, out);
}

// Round 17
// 154.081 us; speedup vs baseline: 1.0684x; 1.0684x over previous
//
#include <hip/hip_runtime.h>
#include <hip/hip_bf16.h>

// Problem constants
#define BATCH 8
#define SEQ   1024
#define CDIM  768
#define HEADS 12
#define HD    64

// Logits kept in t' = log2(e) * (s - o) units (native exp2/log2).
// Coarse histogram: 2048 bins over t' in [-24, 0]; built from a stratified
// 1/8 subsample (kT=0 rows of even chunks) cached as bf16 during sweep 1.
#define NB1    2048
#define TMIN2  (-24.0f)
#define W2     (24.0f / (float)NB1)
#define INV_W2 ((float)NB1 / 24.0f)
#define HLSTR  (NB1 + 8)              // LDS copy stride: +8 banks
#define K_SUB  314573u                // int(12M*0.2)/8
#define QSCALE 0.18033688011112042f   // 0.125 * log2(e)

typedef __attribute__((ext_vector_type(8)))  short bf16x8;
typedef __attribute__((ext_vector_type(4)))  short bf16x4;
typedef __attribute__((ext_vector_type(4)))  float f32x4;
typedef __attribute__((ext_vector_type(16))) float f32x16;
typedef __attribute__((ext_vector_type(4)))  unsigned u32x4;
typedef __attribute__((ext_vector_type(2)))  unsigned u32x2;

#define MFMA16(a, b, c) __builtin_amdgcn_mfma_f32_16x16x32_bf16(a, b, c, 0, 0, 0)
#define MFMA32(a, b, c) __builtin_amdgcn_mfma_f32_32x32x16_bf16(a, b, c, 0, 0, 0)
#define EXP2(x) __builtin_amdgcn_exp2f(x)
#define LOG2(x) __builtin_amdgcn_logf(x)

// HW packed f32->bf16 (RNE): src0 -> lo16, src1 -> hi16.
__device__ inline unsigned cvtpk(float lo, float hi) {
    unsigned r;
    asm("v_cvt_pk_bf16_f32 %0, %1, %2" : "=v"(r) : "v"(lo), "v"(hi));
    return r;
}

// ---------------------------------------------------------------------------
// Prep (fused): blocks [0,3072) convert x fp32->bf16; [3072,3504) transpose
// W_qkv; [3504,3648) transpose W_proj.  Blocks [0,64) also zero the global
// histogram (replaces the hipMemsetAsync dispatch).
// ---------------------------------------------------------------------------
__global__ __launch_bounds__(256) void prep_all(const float* __restrict__ x,
                                                const float* __restrict__ Wq,
                                                const float* __restrict__ Wp,
                                                short* __restrict__ xb,
                                                short* __restrict__ wqt,
                                                short* __restrict__ wpt,
                                                unsigned* __restrict__ hist) {
    __shared__ float ls[64][68];
    int bid = blockIdx.x, tid = threadIdx.x;
    if (bid < 64) hist[bid * 256 + tid] = 0u;   // 64*256 = 16384 = 8*NB1
    if (bid < 3072) {
        int i = bid * 256 + tid;   // 786432 == X_ELEMS/8 exactly
        float4 a = *reinterpret_cast<const float4*>(&x[(size_t)i * 8]);
        float4 b = *reinterpret_cast<const float4*>(&x[(size_t)i * 8 + 4]);
        u32x4 w = {cvtpk(a.x, a.y), cvtpk(a.z, a.w), cvtpk(b.x, b.y), cvtpk(b.z, b.w)};
        *reinterpret_cast<u32x4*>(&xb[(size_t)i * 8]) = w;
        return;
    }
    const float* in;
    short* out;
    int C, t;
    if (bid < 3504) { t = bid - 3072; in = Wq; out = wqt; C = 2304; }
    else            { t = bid - 3504; in = Wp; out = wpt; C = 768; }
    int r0 = (t % 12) * 64, c0 = (t / 12) * 64;
#pragma unroll
    for (int it = 0; it < 4; ++it) {
        int rr = it * 16 + (tid >> 4);
        int cc = (tid & 15) * 4;
        float4 d = *reinterpret_cast<const float4*>(&in[(size_t)(r0 + rr) * C + c0 + cc]);
        ls[rr][cc + 0] = d.x; ls[rr][cc + 1] = d.y; ls[rr][cc + 2] = d.z; ls[rr][cc + 3] = d.w;
    }
    __syncthreads();
#pragma unroll
    for (int it = 0; it < 2; ++it) {
        int orow = it * 32 + (tid >> 3);
        int oc = (tid & 7) * 8;
        u32x4 w = {cvtpk(ls[oc + 0][orow], ls[oc + 1][orow]),
                   cvtpk(ls[oc + 2][orow], ls[oc + 3][orow]),
                   cvtpk(ls[oc + 4][orow], ls[oc + 5][orow]),
                   cvtpk(ls[oc + 6][orow], ls[oc + 7][orow])};
        *reinterpret_cast<u32x4*>(&out[(size_t)(c0 + orow) * 768 + r0 + oc]) = w;
    }
}

// ---------------------------------------------------------------------------
// Kernel 1: qkv = xb @ Wqt^T via MFMA with T14 split staging (best measured).
// Writes bf16 q (x QSCALE), k [bh][n][d], V transposed vt [bh][d][n].
// ---------------------------------------------------------------------------
__global__ __launch_bounds__(256) void qkv_mfma(const short* __restrict__ A,
                                                const short* __restrict__ Bt,
                                                __hip_bfloat16* __restrict__ q,
                                                __hip_bfloat16* __restrict__ k,
                                                __hip_bfloat16* __restrict__ vt) {
    const int K = 768;
    __shared__ short As[128 * 64];
    __shared__ short Bs[128 * 64];
    int tM = blockIdx.x * 128, tN = blockIdx.y * 128;
    int tid = threadIdx.x, wave = tid >> 6, lane = tid & 63, lg = lane >> 4, lc = lane & 15;
    int wr = wave >> 1, wc = wave & 1;
    int srow = tid >> 3, scol = (tid & 7) * 8;
    f32x4 acc[4][4] = {};

    bf16x8 sa[4], sb[4];
#pragma unroll
    for (int j = 0; j < 4; ++j) {
        int r = j * 32 + srow;
        sa[j] = *(const bf16x8*)&A[(size_t)(tM + r) * K + scol];
        sb[j] = *(const bf16x8*)&Bt[(size_t)(tN + r) * K + scol];
    }
#pragma unroll
    for (int j = 0; j < 4; ++j) {
        int r = j * 32 + srow;
        int sw = scol ^ ((r & 7) << 3);
        *(bf16x8*)&As[r * 64 + sw] = sa[j];
        *(bf16x8*)&Bs[r * 64 + sw] = sb[j];
    }
    __syncthreads();

    for (int kc = 0; kc < K; kc += 64) {
        if (kc + 64 < K) {
#pragma unroll
            for (int j = 0; j < 4; ++j) {
                int r = j * 32 + srow;
                sa[j] = *(const bf16x8*)&A[(size_t)(tM + r) * K + kc + 64 + scol];
                sb[j] = *(const bf16x8*)&Bt[(size_t)(tN + r) * K + kc + 64 + scol];
            }
        }
        bf16x8 af[4][2], bfr[4][2];
#pragma unroll
        for (int m4 = 0; m4 < 4; ++m4) {
            int r = wr * 64 + m4 * 16 + lc;
            int sw = (r & 7) << 3;
            af[m4][0] = *(bf16x8*)&As[r * 64 + ((lg * 8) ^ sw)];
            af[m4][1] = *(bf16x8*)&As[r * 64 + ((32 + lg * 8) ^ sw)];
        }
#pragma unroll
        for (int n4 = 0; n4 < 4; ++n4) {
            int r = wc * 64 + n4 * 16 + lc;
            int sw = (r & 7) << 3;
            bfr[n4][0] = *(bf16x8*)&Bs[r * 64 + ((lg * 8) ^ sw)];
            bfr[n4][1] = *(bf16x8*)&Bs[r * 64 + ((32 + lg * 8) ^ sw)];
        }
#pragma unroll
        for (int m4 = 0; m4 < 4; ++m4)
#pragma unroll
            for (int n4 = 0; n4 < 4; ++n4) {
                acc[m4][n4] = MFMA16(af[m4][0], bfr[n4][0], acc[m4][n4]);
                acc[m4][n4] = MFMA16(af[m4][1], bfr[n4][1], acc[m4][n4]);
            }
        __syncthreads();
        if (kc + 64 < K) {
#pragma unroll
            for (int j = 0; j < 4; ++j) {
                int r = j * 32 + srow;
                int sw = scol ^ ((r & 7) << 3);
                *(bf16x8*)&As[r * 64 + sw] = sa[j];
                *(bf16x8*)&Bs[r * 64 + sw] = sb[j];
            }
            __syncthreads();
        }
    }
    int three = tN / 768;
    int cbase = tN - three * 768 + wc * 64;
    if (three == 2) {
#pragma unroll
        for (int m4 = 0; m4 < 4; ++m4) {
            int row0 = tM + wr * 64 + m4 * 16 + lg * 4;
            int b = row0 >> 10, n0 = row0 & 1023;
#pragma unroll
            for (int n4 = 0; n4 < 4; ++n4) {
                int cw = cbase + n4 * 16 + lc;
                int h = cw >> 6, d = cw & 63;
                u32x2 w = {cvtpk(acc[m4][n4][0], acc[m4][n4][1]),
                           cvtpk(acc[m4][n4][2], acc[m4][n4][3])};
                *reinterpret_cast<u32x2*>(
                    &vt[(((size_t)(b * HEADS + h) * 64 + d) << 10) + n0]) = w;
            }
        }
    } else {
        __hip_bfloat16* dst = (three == 0) ? q : k;
#pragma unroll
        for (int m4 = 0; m4 < 4; ++m4)
#pragma unroll
            for (int n4 = 0; n4 < 4; ++n4) {
                int cw = cbase + n4 * 16 + lc;
                int h = cw >> 6, d = cw & 63;
#pragma unroll
                for (int r = 0; r < 4; r += 2) {
                    int row = tM + wr * 64 + m4 * 16 + lg * 4 + r;
                    int b = row >> 10, n = row & 1023;
                    float v0 = acc[m4][n4][r], v1 = acc[m4][n4][r + 1];
                    if (three == 0) { v0 *= QSCALE; v1 *= QSCALE; }
                    unsigned w = cvtpk(v0, v1);
                    size_t base = (((size_t)(b * HEADS + h) << 10) + n) * HD + d;
                    *(unsigned short*)&dst[base] = (unsigned short)w;
                    *(unsigned short*)&dst[base + HD] = (unsigned short)(w >> 16);
                }
            }
    }
}

// ---------------------------------------------------------------------------
// Kernel 2: single-sweep stats + T1 XCD swizzle.
// lsum = sum exp2(s') -> o = log2(lsum); 1/8 stratified sample cached in
// regs during the sweep, binned after o.  Grid = 768 (12 heads per XCD).
// ---------------------------------------------------------------------------
__global__ __launch_bounds__(256) void stats_mfma(const short* __restrict__ q,
                                                  const short* __restrict__ k,
                                                  float* __restrict__ orow,
                                                  unsigned* __restrict__ hist) {
    __shared__ short kls[8192];             // [128 k][64 d], XOR-swizzled
    __shared__ unsigned hl[2 * HLSTR];
    int bid = (blockIdx.x & 7) * 96 + (blockIdx.x >> 3);   // XCD-contiguous heads
    int grp = bid & 7;
    int bh = bid >> 3;
    int b = bh / HEADS;
    int tid = threadIdx.x, wave = tid >> 6, lane = tid & 63;
    int ql = lane & 31, h = lane >> 5;
    const short* kbase = k + (size_t)bh * SEQ * HD;
    int qrow0 = grp * 128 + wave * 32;
    const short* qbase = q + ((size_t)bh * SEQ + qrow0) * HD;
    bf16x8 qf[4];
#pragma unroll
    for (int f = 0; f < 4; ++f)
        qf[f] = *(const bf16x8*)&qbase[ql * 64 + f * 16 + h * 8];

    for (int i = tid; i < 2 * HLSTR; i += 256) hl[i] = 0;

    int srow = tid >> 3, scol = (tid & 7) * 8;
    unsigned scache[4][8];   // even chunks' kT=0 S-values, packed bf16

    bf16x8 st[4];
#pragma unroll
    for (int j = 0; j < 4; ++j)
        st[j] = *(const bf16x8*)&kbase[(size_t)(j * 32 + srow) * 64 + scol];
#pragma unroll
    for (int j = 0; j < 4; ++j) {
        int r = j * 32 + srow;
        *(bf16x8*)&kls[r * 64 + (scol ^ ((r & 7) << 3))] = st[j];
    }
    __syncthreads();
    float lsum = 0.f;
#pragma unroll
    for (int c = 0; c < 8; ++c) {
        if (c < 7) {
#pragma unroll
            for (int j = 0; j < 4; ++j)
                st[j] = *(const bf16x8*)&kbase[(size_t)((c + 1) * 128 + j * 32 + srow) * 64 + scol];
        }
#pragma unroll
        for (int kT = 0; kT < 4; ++kT) {
            f32x16 acc = {};
#pragma unroll
            for (int f = 0; f < 4; ++f) {
                int krow = kT * 32 + ql;
                bf16x8 af = *(bf16x8*)&kls[krow * 64 + ((f * 16 + h * 8) ^ ((krow & 7) << 3))];
                acc = MFMA32(af, qf[f], acc);
            }
            if (kT == 0 && (c & 1) == 0) {
#pragma unroll
                for (int i = 0; i < 8; ++i)
                    scache[c >> 1][i] = cvtpk(acc[2 * i], acc[2 * i + 1]);
            }
            float s = 0.f;
#pragma unroll
            for (int r = 0; r < 16; ++r) s += EXP2(acc[r]);
            lsum += s;
        }
        __syncthreads();
        if (c < 7) {
#pragma unroll
            for (int j = 0; j < 4; ++j) {
                int r = j * 32 + srow;
                *(bf16x8*)&kls[r * 64 + (scol ^ ((r & 7) << 3))] = st[j];
            }
            __syncthreads();
        }
    }
    lsum += __shfl_xor(lsum, 32, 64);
    float o = LOG2(lsum);
    if (h == 0) orow[(size_t)bh * SEQ + qrow0 + ql] = o;

    // bin the cached 1/8 sample
    unsigned coff = (lane & 1) * HLSTR;
#pragma unroll
    for (int cc = 0; cc < 4; ++cc)
#pragma unroll
        for (int i = 0; i < 8; ++i) {
            unsigned w = scache[cc][i];
            float s0 = __builtin_bit_cast(float, w << 16);
            float s1 = __builtin_bit_cast(float, w & 0xffff0000u);
            int b0 = (int)((s0 - o) * INV_W2 + (float)NB1);
            int b1 = (int)((s1 - o) * INV_W2 + (float)NB1);
            b0 = b0 < 0 ? 0 : (b0 > NB1 - 1 ? NB1 - 1 : b0);
            b1 = b1 < 0 ? 0 : (b1 > NB1 - 1 ? NB1 - 1 : b1);
            atomicAdd(&hl[coff + b0], 1u);
            atomicAdd(&hl[coff + b1], 1u);
        }
    __syncthreads();
    unsigned* hb = hist + (size_t)b * NB1;
    for (int i = tid; i < NB1; i += 256) {
        unsigned s = hl[i] + hl[HLSTR + i];
        if (s) atomicAdd(&hb[i], s);
    }
}

// ---------------------------------------------------------------------------
// Kernel 3: per-batch threshold (subsampled counts: K_SUB)
// ---------------------------------------------------------------------------
__global__ __launch_bounds__(256) void find_thr(const unsigned* __restrict__ hist,
                                                float* __restrict__ thr) {
    __shared__ unsigned cs[256];
    int b = blockIdx.x, tid = threadIdx.x;
    const unsigned* hb = hist + (size_t)b * NB1;
    unsigned s = 0;
#pragma unroll
    for (int i = 0; i < 8; ++i) s += hb[tid * 8 + i];
    cs[tid] = s;
    __syncthreads();
    unsigned suf = 0;
    for (int j = tid; j < 256; ++j) suf += cs[j];
    unsigned above = suf - cs[tid];
    if (suf >= K_SUB && above < K_SUB) {
        unsigned acc = above;
        for (int bb = 7; bb >= 0; --bb) {
            acc += hb[tid * 8 + bb];
            if (acc >= K_SUB) {
                thr[b] = TMIN2 + (float)(tid * 8 + bb) * W2;
                break;
            }
        }
    }
}

// ---------------------------------------------------------------------------
// Kernel 4: k-split PV + T1 XCD swizzle.  Block = 64 q-rows; 4 waves =
// {rowhalf} x {khalf}.  Grid = 1536 (12 heads per XCD; K/V L2-resident).
// ---------------------------------------------------------------------------
__global__ __launch_bounds__(256) void pv_mfma(const short* __restrict__ q,
                                               const short* __restrict__ k,
                                               const short* __restrict__ vt,
                                               const float* __restrict__ orow,
                                               const float* __restrict__ thr,
                                               __hip_bfloat16* __restrict__ aout) {
    __shared__ __align__(16) char smem[32768];
    short* klsA = (short*)smem;
    short* klsB = (short*)(smem + 8192);
    short* vlsA = (short*)(smem + 16384);
    short* vlsB = (short*)(smem + 24576);
    float* comb = (float*)smem;

    int bid = (blockIdx.x & 7) * 192 + (blockIdx.x >> 3);   // XCD-contiguous heads
    int grp = bid & 15;
    int bh = bid >> 4;
    int b = bh / HEADS, hh = bh % HEADS;
    int tid = threadIdx.x, wave = tid >> 6, lane = tid & 63;
    int ql = lane & 31, h = lane >> 5;
    int rh = wave & 1;
    int kh = wave >> 1;
    const short* kbase = k + (size_t)bh * SEQ * HD;
    const short* vtb = vt + (size_t)bh * HD * SEQ;
    int qrow0 = grp * 64 + rh * 32;
    const short* qbase = q + ((size_t)bh * SEQ + qrow0) * HD;
    bf16x8 qf[4];
#pragma unroll
    for (int f = 0; f < 4; ++f)
        qf[f] = *(const bf16x8*)&qbase[ql * 64 + f * 16 + h * 8];
    float o = orow[(size_t)bh * SEQ + qrow0 + ql];
    float tt = thr[b];
    f32x16 oacc[2] = {};
    f32x16 minus_o;
#pragma unroll
    for (int r = 0; r < 16; ++r) minus_o[r] = -o;

    short* kls = kh ? klsB : klsA;
    short* vls = kh ? vlsB : vlsA;

    int sp = tid >> 7;
    int tl = tid & 127;
    int srow = tl >> 3, scol = (tl & 7) * 8;
    short* skls = sp ? klsB : klsA;
    short* svls = sp ? vlsB : vlsA;

    bf16x8 sk[4], sv[4];
    int cc0 = sp * 8;
#pragma unroll
    for (int j = 0; j < 4; ++j) {
        int r = j * 16 + srow;
        sk[j] = *(const bf16x8*)&kbase[(size_t)(cc0 * 64 + r) * 64 + scol];
        sv[j] = *(const bf16x8*)&vtb[((size_t)r << 10) + cc0 * 64 + scol];
    }
#pragma unroll
    for (int j = 0; j < 4; ++j) {
        int r = j * 16 + srow;
        *(bf16x8*)&skls[r * 64 + (scol ^ ((r & 7) << 3))] = sk[j];
        *(bf16x8*)&svls[r * 64 + (scol ^ ((r & 7) << 3))] = sv[j];
    }
    __syncthreads();

    for (int c = 0; c < 8; ++c) {
        if (c < 7) {
            int cc = sp * 8 + c + 1;
#pragma unroll
            for (int j = 0; j < 4; ++j) {
                int r = j * 16 + srow;
                sk[j] = *(const bf16x8*)&kbase[(size_t)(cc * 64 + r) * 64 + scol];
                sv[j] = *(const bf16x8*)&vtb[((size_t)r << 10) + cc * 64 + scol];
            }
        }
#pragma unroll
        for (int kT = 0; kT < 2; ++kT) {
            f32x16 acc = minus_o;
#pragma unroll
            for (int f = 0; f < 4; ++f) {
                int krow = kT * 32 + ql;
                bf16x8 af = *(bf16x8*)&kls[krow * 64 + ((f * 16 + h * 8) ^ ((krow & 7) << 3))];
                acc = MFMA32(af, qf[f], acc);
            }
            float p[16];
#pragma unroll
            for (int r = 0; r < 16; ++r)
                p[r] = (acc[r] >= tt) ? EXP2(acc[r]) : 0.f;
            unsigned c8[8];
#pragma unroll
            for (int i = 0; i < 8; ++i) c8[i] = cvtpk(p[2 * i], p[2 * i + 1]);
#pragma unroll
            for (int s = 0; s < 2; ++s) {
                unsigned a1 = c8[4 * s],     b1 = c8[4 * s + 2];
                unsigned a2 = c8[4 * s + 1], b2 = c8[4 * s + 3];
                asm("v_permlane32_swap_b32 %0, %1" : "+v"(a1), "+v"(b1));
                asm("v_permlane32_swap_b32 %0, %1" : "+v"(a2), "+v"(b2));
                u32x4 W = {a1, a2, b1, b2};
                bf16x8 pa = __builtin_bit_cast(bf16x8, W);
#pragma unroll
                for (int dt = 0; dt < 2; ++dt) {
                    int vrow = dt * 32 + ql;
                    int vcol = (kT * 32 + s * 16 + h * 8) ^ ((vrow & 7) << 3);
                    bf16x8 vf = *(bf16x8*)&vls[vrow * 64 + vcol];
                    oacc[dt] = MFMA32(pa, vf, oacc[dt]);
                }
            }
        }
        __syncthreads();
        if (c < 7) {
#pragma unroll
            for (int j = 0; j < 4; ++j) {
                int r = j * 16 + srow;
                *(bf16x8*)&skls[r * 64 + (scol ^ ((r & 7) << 3))] = sk[j];
                *(bf16x8*)&svls[r * 64 + (scol ^ ((r & 7) << 3))] = sv[j];
            }
            __syncthreads();
        }
    }

    if (kh == 1) {
#pragma unroll
        for (int dt = 0; dt < 2; ++dt)
#pragma unroll
            for (int r = 0; r < 16; ++r) {
                int crow = (r & 3) + 8 * (r >> 2) + 4 * h;
                comb[(rh * 32 + crow) * 65 + dt * 32 + ql] = oacc[dt][r];
            }
    }
    __syncthreads();
    if (kh == 1) return;
#pragma unroll
    for (int dt = 0; dt < 2; ++dt)
#pragma unroll
        for (int r = 0; r < 16; ++r) {
            int crow = (r & 3) + 8 * (r >> 2) + 4 * h;
            oacc[dt][r] += comb[(rh * 32 + crow) * 65 + dt * 32 + ql];
        }
#pragma unroll
    for (int dt = 0; dt < 2; ++dt)
#pragma unroll
        for (int r = 0; r < 16; r += 2) {
            int qr0 = qrow0 + (r & 3) + 8 * (r >> 2) + 4 * h;
            int qr1 = qrow0 + ((r + 1) & 3) + 8 * ((r + 1) >> 2) + 4 * h;
            unsigned w = cvtpk(oacc[dt][r], oacc[dt][r + 1]);
            *(unsigned short*)&aout[((size_t)b * SEQ + qr0) * CDIM + hh * 64 + dt * 32 + ql] =
                (unsigned short)w;
            *(unsigned short*)&aout[((size_t)b * SEQ + qr1) * CDIM + hh * 64 + dt * 32 + ql] =
                (unsigned short)(w >> 16);
        }
}

// ---------------------------------------------------------------------------
// Kernel 5: out = aoutb @ Wpt^T + b_proj + origin (MFMA, fp32 epilogue),
// T14 split staging.
// ---------------------------------------------------------------------------
__global__ __launch_bounds__(256) void proj_mfma(const short* __restrict__ A,
                                                 const short* __restrict__ Bt,
                                                 const float* __restrict__ bias,
                                                 const float* __restrict__ origin,
                                                 float* __restrict__ out) {
    const int K = 768, NN = 768;
    __shared__ short As[128 * 64];
    __shared__ short Bs[128 * 64];
    int tM = blockIdx.x * 128, tN = blockIdx.y * 128;
    int tid = threadIdx.x, wave = tid >> 6, lane = tid & 63, lg = lane >> 4, lc = lane & 15;
    int wr = wave >> 1, wc = wave & 1;
    int srow = tid >> 3, scol = (tid & 7) * 8;
    f32x4 acc[4][4] = {};

    bf16x8 sa[4], sb[4];
#pragma unroll
    for (int j = 0; j < 4; ++j) {
        int r = j * 32 + srow;
        sa[j] = *(const bf16x8*)&A[(size_t)(tM + r) * K + scol];
        sb[j] = *(const bf16x8*)&Bt[(size_t)(tN + r) * K + scol];
    }
#pragma unroll
    for (int j = 0; j < 4; ++j) {
        int r = j * 32 + srow;
        int sw = scol ^ ((r & 7) << 3);
        *(bf16x8*)&As[r * 64 + sw] = sa[j];
        *(bf16x8*)&Bs[r * 64 + sw] = sb[j];
    }
    __syncthreads();

    for (int kc = 0; kc < K; kc += 64) {
        if (kc + 64 < K) {
#pragma unroll
            for (int j = 0; j < 4; ++j) {
                int r = j * 32 + srow;
                sa[j] = *(const bf16x8*)&A[(size_t)(tM + r) * K + kc + 64 + scol];
                sb[j] = *(const bf16x8*)&Bt[(size_t)(tN + r) * K + kc + 64 + scol];
            }
        }
        bf16x8 af[4][2], bfr[4][2];
#pragma unroll
        for (int m4 = 0; m4 < 4; ++m4) {
            int r = wr * 64 + m4 * 16 + lc;
            int sw = (r & 7) << 3;
            af[m4][0] = *(bf16x8*)&As[r * 64 + ((lg * 8) ^ sw)];
            af[m4][1] = *(bf16x8*)&As[r * 64 + ((32 + lg * 8) ^ sw)];
        }
#pragma unroll
        for (int n4 = 0; n4 < 4; ++n4) {
            int r = wc * 64 + n4 * 16 + lc;
            int sw = (r & 7) << 3;
            bfr[n4][0] = *(bf16x8*)&Bs[r * 64 + ((lg * 8) ^ sw)];
            bfr[n4][1] = *(bf16x8*)&Bs[r * 64 + ((32 + lg * 8) ^ sw)];
        }
#pragma unroll
        for (int m4 = 0; m4 < 4; ++m4)
#pragma unroll
            for (int n4 = 0; n4 < 4; ++n4) {
                acc[m4][n4] = MFMA16(af[m4][0], bfr[n4][0], acc[m4][n4]);
                acc[m4][n4] = MFMA16(af[m4][1], bfr[n4][1], acc[m4][n4]);
            }
        __syncthreads();
        if (kc + 64 < K) {
#pragma unroll
            for (int j = 0; j < 4; ++j) {
                int r = j * 32 + srow;
                int sw = scol ^ ((r & 7) << 3);
                *(bf16x8*)&As[r * 64 + sw] = sa[j];
                *(bf16x8*)&Bs[r * 64 + sw] = sb[j];
            }
            __syncthreads();
        }
    }
#pragma unroll
    for (int m4 = 0; m4 < 4; ++m4)
#pragma unroll
        for (int n4 = 0; n4 < 4; ++n4)
#pragma unroll
            for (int r = 0; r < 4; ++r) {
                int row = tM + wr * 64 + m4 * 16 + lg * 4 + r;
                int col = tN + wc * 64 + n4 * 16 + lc;
                out[(size_t)row * NN + col] = acc[m4][n4][r] + bias[col] + origin[(size_t)row * NN + col];
            }
}

// ---------------------------------------------------------------------------
extern "C" void kernel_launch(void* const* d_in, const int* in_sizes, int n_in,
                              void* d_out, int out_size, void* d_ws, size_t ws_size,
                              hipStream_t stream) {
    const float* x      = (const float*)d_in[0];
    const float* origin = (const float*)d_in[1];
    const float* W_qkv  = (const float*)d_in[2];
    const float* W_proj = (const float*)d_in[3];
    const float* b_proj = (const float*)d_in[4];
    float* out = (float*)d_out;
    char* ws = (char*)d_ws;

    const size_t QKV_ELEMS = (size_t)BATCH * HEADS * SEQ * HD;   // 6291456
    const size_t X_ELEMS   = (size_t)BATCH * SEQ * CDIM;         // 6291456
    size_t off = 0;
    short* xb  = (short*)(ws + off); off += X_ELEMS * 2;
    short* wqt = (short*)(ws + off); off += (size_t)2304 * 768 * 2;
    short* wpt = (short*)(ws + off); off += (size_t)768 * 768 * 2;
    short* q   = (short*)(ws + off); off += QKV_ELEMS * 2;
    short* k   = (short*)(ws + off); off += QKV_ELEMS * 2;
    short* vt  = (short*)(ws + off); off += QKV_ELEMS * 2;
    short* aoutb = (short*)(ws + off); off += QKV_ELEMS * 2;
    float* orow = (float*)(ws + off); off += (size_t)BATCH * HEADS * SEQ * 4;
    unsigned* hist = (unsigned*)(ws + off); off += (size_t)BATCH * NB1 * 4;
    float* thr = (float*)(ws + off); off += 8 * 4;

    prep_all<<<dim3(3648), 256, 0, stream>>>(x, W_qkv, W_proj, xb, wqt, wpt, hist);
    qkv_mfma<<<dim3(64, 18), 256, 0, stream>>>(xb, wqt,
                                               (__hip_bfloat16*)q, (__hip_bfloat16*)k, (__hip_bfloat16*)vt);
    stats_mfma<<<dim3(BATCH * HEADS * 8), 256, 0, stream>>>(q, k, orow, hist);
    find_thr<<<dim3(BATCH), 256, 0, stream>>>(hist, thr);
    pv_mfma<<<dim3(BATCH * HEADS * 16), 256, 0, stream>>>(q, k, vt, orow, thr,
                                                          (__hip_bfloat16*)aoutb);
    proj_mfma<<<dim3(64, 6), 256, 0, stream>>>(aoutb, wpt, b_proj, origin, out);
}

// Round 18
// 153.043 us; speedup vs baseline: 1.0757x; 1.0068x over previous
//
#include <hip/hip_runtime.h>
#include <hip/hip_bf16.h>

// Problem constants
#define BATCH 8
#define SEQ   1024
#define CDIM  768
#define HEADS 12
#define HD    64

// Logits kept in t' = log2(e) * (s - o) units (native exp2/log2).
// Coarse histogram: 2048 bins over t' in [-24, 0]; built from a stratified
// 1/8 subsample (kT=0 rows of even chunks) cached as bf16 during sweep 1.
#define NB1    2048
#define TMIN2  (-24.0f)
#define W2     (24.0f / (float)NB1)
#define INV_W2 ((float)NB1 / 24.0f)
#define HLSTR  (NB1 + 8)              // single LDS histogram copy (+pad)
#define K_SUB  314573u                // int(12M*0.2)/8
#define QSCALE 0.18033688011112042f   // 0.125 * log2(e)

typedef __attribute__((ext_vector_type(8)))  short bf16x8;
typedef __attribute__((ext_vector_type(4)))  short bf16x4;
typedef __attribute__((ext_vector_type(4)))  float f32x4;
typedef __attribute__((ext_vector_type(16))) float f32x16;
typedef __attribute__((ext_vector_type(4)))  unsigned u32x4;
typedef __attribute__((ext_vector_type(2)))  unsigned u32x2;

#define MFMA16(a, b, c) __builtin_amdgcn_mfma_f32_16x16x32_bf16(a, b, c, 0, 0, 0)
#define MFMA32(a, b, c) __builtin_amdgcn_mfma_f32_32x32x16_bf16(a, b, c, 0, 0, 0)
#define EXP2(x) __builtin_amdgcn_exp2f(x)
#define LOG2(x) __builtin_amdgcn_logf(x)

// HW packed f32->bf16 (RNE): src0 -> lo16, src1 -> hi16.
__device__ inline unsigned cvtpk(float lo, float hi) {
    unsigned r;
    asm("v_cvt_pk_bf16_f32 %0, %1, %2" : "=v"(r) : "v"(lo), "v"(hi));
    return r;
}

// ---------------------------------------------------------------------------
// Prep (fused): blocks [0,3072) convert x fp32->bf16; [3072,3504) transpose
// W_qkv; [3504,3648) transpose W_proj.  Blocks [0,64) also zero the global
// histogram (replaces the hipMemsetAsync dispatch).
// ---------------------------------------------------------------------------
__global__ __launch_bounds__(256) void prep_all(const float* __restrict__ x,
                                                const float* __restrict__ Wq,
                                                const float* __restrict__ Wp,
                                                short* __restrict__ xb,
                                                short* __restrict__ wqt,
                                                short* __restrict__ wpt,
                                                unsigned* __restrict__ hist) {
    __shared__ float ls[64][68];
    int bid = blockIdx.x, tid = threadIdx.x;
    if (bid < 64) hist[bid * 256 + tid] = 0u;   // 64*256 = 16384 = 8*NB1
    if (bid < 3072) {
        int i = bid * 256 + tid;   // 786432 == X_ELEMS/8 exactly
        float4 a = *reinterpret_cast<const float4*>(&x[(size_t)i * 8]);
        float4 b = *reinterpret_cast<const float4*>(&x[(size_t)i * 8 + 4]);
        u32x4 w = {cvtpk(a.x, a.y), cvtpk(a.z, a.w), cvtpk(b.x, b.y), cvtpk(b.z, b.w)};
        *reinterpret_cast<u32x4*>(&xb[(size_t)i * 8]) = w;
        return;
    }
    const float* in;
    short* out;
    int C, t;
    if (bid < 3504) { t = bid - 3072; in = Wq; out = wqt; C = 2304; }
    else            { t = bid - 3504; in = Wp; out = wpt; C = 768; }
    int r0 = (t % 12) * 64, c0 = (t / 12) * 64;
#pragma unroll
    for (int it = 0; it < 4; ++it) {
        int rr = it * 16 + (tid >> 4);
        int cc = (tid & 15) * 4;
        float4 d = *reinterpret_cast<const float4*>(&in[(size_t)(r0 + rr) * C + c0 + cc]);
        ls[rr][cc + 0] = d.x; ls[rr][cc + 1] = d.y; ls[rr][cc + 2] = d.z; ls[rr][cc + 3] = d.w;
    }
    __syncthreads();
#pragma unroll
    for (int it = 0; it < 2; ++it) {
        int orow = it * 32 + (tid >> 3);
        int oc = (tid & 7) * 8;
        u32x4 w = {cvtpk(ls[oc + 0][orow], ls[oc + 1][orow]),
                   cvtpk(ls[oc + 2][orow], ls[oc + 3][orow]),
                   cvtpk(ls[oc + 4][orow], ls[oc + 5][orow]),
                   cvtpk(ls[oc + 6][orow], ls[oc + 7][orow])};
        *reinterpret_cast<u32x4*>(&out[(size_t)(c0 + orow) * 768 + r0 + oc]) = w;
    }
}

// ---------------------------------------------------------------------------
// Kernel 1: qkv = xb @ Wqt^T via MFMA with T14 split staging (best measured).
// Writes bf16 q (x QSCALE), k [bh][n][d], V transposed vt [bh][d][n].
// ---------------------------------------------------------------------------
__global__ __launch_bounds__(256) void qkv_mfma(const short* __restrict__ A,
                                                const short* __restrict__ Bt,
                                                __hip_bfloat16* __restrict__ q,
                                                __hip_bfloat16* __restrict__ k,
                                                __hip_bfloat16* __restrict__ vt) {
    const int K = 768;
    __shared__ short As[128 * 64];
    __shared__ short Bs[128 * 64];
    int tM = blockIdx.x * 128, tN = blockIdx.y * 128;
    int tid = threadIdx.x, wave = tid >> 6, lane = tid & 63, lg = lane >> 4, lc = lane & 15;
    int wr = wave >> 1, wc = wave & 1;
    int srow = tid >> 3, scol = (tid & 7) * 8;
    f32x4 acc[4][4] = {};

    bf16x8 sa[4], sb[4];
#pragma unroll
    for (int j = 0; j < 4; ++j) {
        int r = j * 32 + srow;
        sa[j] = *(const bf16x8*)&A[(size_t)(tM + r) * K + scol];
        sb[j] = *(const bf16x8*)&Bt[(size_t)(tN + r) * K + scol];
    }
#pragma unroll
    for (int j = 0; j < 4; ++j) {
        int r = j * 32 + srow;
        int sw = scol ^ ((r & 7) << 3);
        *(bf16x8*)&As[r * 64 + sw] = sa[j];
        *(bf16x8*)&Bs[r * 64 + sw] = sb[j];
    }
    __syncthreads();

    for (int kc = 0; kc < K; kc += 64) {
        if (kc + 64 < K) {
#pragma unroll
            for (int j = 0; j < 4; ++j) {
                int r = j * 32 + srow;
                sa[j] = *(const bf16x8*)&A[(size_t)(tM + r) * K + kc + 64 + scol];
                sb[j] = *(const bf16x8*)&Bt[(size_t)(tN + r) * K + kc + 64 + scol];
            }
        }
        bf16x8 af[4][2], bfr[4][2];
#pragma unroll
        for (int m4 = 0; m4 < 4; ++m4) {
            int r = wr * 64 + m4 * 16 + lc;
            int sw = (r & 7) << 3;
            af[m4][0] = *(bf16x8*)&As[r * 64 + ((lg * 8) ^ sw)];
            af[m4][1] = *(bf16x8*)&As[r * 64 + ((32 + lg * 8) ^ sw)];
        }
#pragma unroll
        for (int n4 = 0; n4 < 4; ++n4) {
            int r = wc * 64 + n4 * 16 + lc;
            int sw = (r & 7) << 3;
            bfr[n4][0] = *(bf16x8*)&Bs[r * 64 + ((lg * 8) ^ sw)];
            bfr[n4][1] = *(bf16x8*)&Bs[r * 64 + ((32 + lg * 8) ^ sw)];
        }
#pragma unroll
        for (int m4 = 0; m4 < 4; ++m4)
#pragma unroll
            for (int n4 = 0; n4 < 4; ++n4) {
                acc[m4][n4] = MFMA16(af[m4][0], bfr[n4][0], acc[m4][n4]);
                acc[m4][n4] = MFMA16(af[m4][1], bfr[n4][1], acc[m4][n4]);
            }
        __syncthreads();
        if (kc + 64 < K) {
#pragma unroll
            for (int j = 0; j < 4; ++j) {
                int r = j * 32 + srow;
                int sw = scol ^ ((r & 7) << 3);
                *(bf16x8*)&As[r * 64 + sw] = sa[j];
                *(bf16x8*)&Bs[r * 64 + sw] = sb[j];
            }
            __syncthreads();
        }
    }
    int three = tN / 768;
    int cbase = tN - three * 768 + wc * 64;
    if (three == 2) {
#pragma unroll
        for (int m4 = 0; m4 < 4; ++m4) {
            int row0 = tM + wr * 64 + m4 * 16 + lg * 4;
            int b = row0 >> 10, n0 = row0 & 1023;
#pragma unroll
            for (int n4 = 0; n4 < 4; ++n4) {
                int cw = cbase + n4 * 16 + lc;
                int h = cw >> 6, d = cw & 63;
                u32x2 w = {cvtpk(acc[m4][n4][0], acc[m4][n4][1]),
                           cvtpk(acc[m4][n4][2], acc[m4][n4][3])};
                *reinterpret_cast<u32x2*>(
                    &vt[(((size_t)(b * HEADS + h) * 64 + d) << 10) + n0]) = w;
            }
        }
    } else {
        __hip_bfloat16* dst = (three == 0) ? q : k;
#pragma unroll
        for (int m4 = 0; m4 < 4; ++m4)
#pragma unroll
            for (int n4 = 0; n4 < 4; ++n4) {
                int cw = cbase + n4 * 16 + lc;
                int h = cw >> 6, d = cw & 63;
#pragma unroll
                for (int r = 0; r < 4; r += 2) {
                    int row = tM + wr * 64 + m4 * 16 + lg * 4 + r;
                    int b = row >> 10, n = row & 1023;
                    float v0 = acc[m4][n4][r], v1 = acc[m4][n4][r + 1];
                    if (three == 0) { v0 *= QSCALE; v1 *= QSCALE; }
                    unsigned w = cvtpk(v0, v1);
                    size_t base = (((size_t)(b * HEADS + h) << 10) + n) * HD + d;
                    *(unsigned short*)&dst[base] = (unsigned short)w;
                    *(unsigned short*)&dst[base + HD] = (unsigned short)(w >> 16);
                }
            }
    }
}

// ---------------------------------------------------------------------------
// Kernel 2: single-sweep stats + T1 XCD swizzle.  Single-copy LDS histogram
// (binning is only the 1/8 reg-cached sample -> contention negligible);
// LDS 32.4 -> 24.3 KB lifts residency 4 -> 6 blocks/CU for latency hiding.
// ---------------------------------------------------------------------------
__global__ __launch_bounds__(256) void stats_mfma(const short* __restrict__ q,
                                                  const short* __restrict__ k,
                                                  float* __restrict__ orow,
                                                  unsigned* __restrict__ hist) {
    __shared__ short kls[8192];             // [128 k][64 d], XOR-swizzled
    __shared__ unsigned hl[HLSTR];          // single copy
    int bid = (blockIdx.x & 7) * 96 + (blockIdx.x >> 3);   // XCD-contiguous heads
    int grp = bid & 7;
    int bh = bid >> 3;
    int b = bh / HEADS;
    int tid = threadIdx.x, wave = tid >> 6, lane = tid & 63;
    int ql = lane & 31, h = lane >> 5;
    const short* kbase = k + (size_t)bh * SEQ * HD;
    int qrow0 = grp * 128 + wave * 32;
    const short* qbase = q + ((size_t)bh * SEQ + qrow0) * HD;
    bf16x8 qf[4];
#pragma unroll
    for (int f = 0; f < 4; ++f)
        qf[f] = *(const bf16x8*)&qbase[ql * 64 + f * 16 + h * 8];

    for (int i = tid; i < HLSTR; i += 256) hl[i] = 0;

    int srow = tid >> 3, scol = (tid & 7) * 8;
    unsigned scache[4][8];   // even chunks' kT=0 S-values, packed bf16

    bf16x8 st[4];
#pragma unroll
    for (int j = 0; j < 4; ++j)
        st[j] = *(const bf16x8*)&kbase[(size_t)(j * 32 + srow) * 64 + scol];
#pragma unroll
    for (int j = 0; j < 4; ++j) {
        int r = j * 32 + srow;
        *(bf16x8*)&kls[r * 64 + (scol ^ ((r & 7) << 3))] = st[j];
    }
    __syncthreads();
    float lsum = 0.f;
#pragma unroll
    for (int c = 0; c < 8; ++c) {
        if (c < 7) {
#pragma unroll
            for (int j = 0; j < 4; ++j)
                st[j] = *(const bf16x8*)&kbase[(size_t)((c + 1) * 128 + j * 32 + srow) * 64 + scol];
        }
#pragma unroll
        for (int kT = 0; kT < 4; ++kT) {
            f32x16 acc = {};
#pragma unroll
            for (int f = 0; f < 4; ++f) {
                int krow = kT * 32 + ql;
                bf16x8 af = *(bf16x8*)&kls[krow * 64 + ((f * 16 + h * 8) ^ ((krow & 7) << 3))];
                acc = MFMA32(af, qf[f], acc);
            }
            if (kT == 0 && (c & 1) == 0) {
#pragma unroll
                for (int i = 0; i < 8; ++i)
                    scache[c >> 1][i] = cvtpk(acc[2 * i], acc[2 * i + 1]);
            }
            float s = 0.f;
#pragma unroll
            for (int r = 0; r < 16; ++r) s += EXP2(acc[r]);
            lsum += s;
        }
        __syncthreads();
        if (c < 7) {
#pragma unroll
            for (int j = 0; j < 4; ++j) {
                int r = j * 32 + srow;
                *(bf16x8*)&kls[r * 64 + (scol ^ ((r & 7) << 3))] = st[j];
            }
            __syncthreads();
        }
    }
    lsum += __shfl_xor(lsum, 32, 64);
    float o = LOG2(lsum);
    if (h == 0) orow[(size_t)bh * SEQ + qrow0 + ql] = o;

    // bin the cached 1/8 sample
#pragma unroll
    for (int cc = 0; cc < 4; ++cc)
#pragma unroll
        for (int i = 0; i < 8; ++i) {
            unsigned w = scache[cc][i];
            float s0 = __builtin_bit_cast(float, w << 16);
            float s1 = __builtin_bit_cast(float, w & 0xffff0000u);
            int b0 = (int)((s0 - o) * INV_W2 + (float)NB1);
            int b1 = (int)((s1 - o) * INV_W2 + (float)NB1);
            b0 = b0 < 0 ? 0 : (b0 > NB1 - 1 ? NB1 - 1 : b0);
            b1 = b1 < 0 ? 0 : (b1 > NB1 - 1 ? NB1 - 1 : b1);
            atomicAdd(&hl[b0], 1u);
            atomicAdd(&hl[b1], 1u);
        }
    __syncthreads();
    unsigned* hb = hist + (size_t)b * NB1;
    for (int i = tid; i < NB1; i += 256) {
        unsigned s = hl[i];
        if (s) atomicAdd(&hb[i], s);
    }
}

// ---------------------------------------------------------------------------
// Kernel 3: per-batch threshold (subsampled counts: K_SUB)
// ---------------------------------------------------------------------------
__global__ __launch_bounds__(256) void find_thr(const unsigned* __restrict__ hist,
                                                float* __restrict__ thr) {
    __shared__ unsigned cs[256];
    int b = blockIdx.x, tid = threadIdx.x;
    const unsigned* hb = hist + (size_t)b * NB1;
    unsigned s = 0;
#pragma unroll
    for (int i = 0; i < 8; ++i) s += hb[tid * 8 + i];
    cs[tid] = s;
    __syncthreads();
    unsigned suf = 0;
    for (int j = tid; j < 256; ++j) suf += cs[j];
    unsigned above = suf - cs[tid];
    if (suf >= K_SUB && above < K_SUB) {
        unsigned acc = above;
        for (int bb = 7; bb >= 0; --bb) {
            acc += hb[tid * 8 + bb];
            if (acc >= K_SUB) {
                thr[b] = TMIN2 + (float)(tid * 8 + bb) * W2;
                break;
            }
        }
    }
}

// ---------------------------------------------------------------------------
// Kernel 4: k-split PV + T1 XCD swizzle.  Block = 64 q-rows; 4 waves =
// {rowhalf} x {khalf}.  Grid = 1536 (12 heads per XCD; K/V L2-resident).
// ---------------------------------------------------------------------------
__global__ __launch_bounds__(256) void pv_mfma(const short* __restrict__ q,
                                               const short* __restrict__ k,
                                               const short* __restrict__ vt,
                                               const float* __restrict__ orow,
                                               const float* __restrict__ thr,
                                               __hip_bfloat16* __restrict__ aout) {
    __shared__ __align__(16) char smem[32768];
    short* klsA = (short*)smem;
    short* klsB = (short*)(smem + 8192);
    short* vlsA = (short*)(smem + 16384);
    short* vlsB = (short*)(smem + 24576);
    float* comb = (float*)smem;

    int bid = (blockIdx.x & 7) * 192 + (blockIdx.x >> 3);   // XCD-contiguous heads
    int grp = bid & 15;
    int bh = bid >> 4;
    int b = bh / HEADS, hh = bh % HEADS;
    int tid = threadIdx.x, wave = tid >> 6, lane = tid & 63;
    int ql = lane & 31, h = lane >> 5;
    int rh = wave & 1;
    int kh = wave >> 1;
    const short* kbase = k + (size_t)bh * SEQ * HD;
    const short* vtb = vt + (size_t)bh * HD * SEQ;
    int qrow0 = grp * 64 + rh * 32;
    const short* qbase = q + ((size_t)bh * SEQ + qrow0) * HD;
    bf16x8 qf[4];
#pragma unroll
    for (int f = 0; f < 4; ++f)
        qf[f] = *(const bf16x8*)&qbase[ql * 64 + f * 16 + h * 8];
    float o = orow[(size_t)bh * SEQ + qrow0 + ql];
    float tt = thr[b];
    f32x16 oacc[2] = {};
    f32x16 minus_o;
#pragma unroll
    for (int r = 0; r < 16; ++r) minus_o[r] = -o;

    short* kls = kh ? klsB : klsA;
    short* vls = kh ? vlsB : vlsA;

    int sp = tid >> 7;
    int tl = tid & 127;
    int srow = tl >> 3, scol = (tl & 7) * 8;
    short* skls = sp ? klsB : klsA;
    short* svls = sp ? vlsB : vlsA;

    bf16x8 sk[4], sv[4];
    int cc0 = sp * 8;
#pragma unroll
    for (int j = 0; j < 4; ++j) {
        int r = j * 16 + srow;
        sk[j] = *(const bf16x8*)&kbase[(size_t)(cc0 * 64 + r) * 64 + scol];
        sv[j] = *(const bf16x8*)&vtb[((size_t)r << 10) + cc0 * 64 + scol];
    }
#pragma unroll
    for (int j = 0; j < 4; ++j) {
        int r = j * 16 + srow;
        *(bf16x8*)&skls[r * 64 + (scol ^ ((r & 7) << 3))] = sk[j];
        *(bf16x8*)&svls[r * 64 + (scol ^ ((r & 7) << 3))] = sv[j];
    }
    __syncthreads();

    for (int c = 0; c < 8; ++c) {
        if (c < 7) {
            int cc = sp * 8 + c + 1;
#pragma unroll
            for (int j = 0; j < 4; ++j) {
                int r = j * 16 + srow;
                sk[j] = *(const bf16x8*)&kbase[(size_t)(cc * 64 + r) * 64 + scol];
                sv[j] = *(const bf16x8*)&vtb[((size_t)r << 10) + cc * 64 + scol];
            }
        }
#pragma unroll
        for (int kT = 0; kT < 2; ++kT) {
            f32x16 acc = minus_o;
#pragma unroll
            for (int f = 0; f < 4; ++f) {
                int krow = kT * 32 + ql;
                bf16x8 af = *(bf16x8*)&kls[krow * 64 + ((f * 16 + h * 8) ^ ((krow & 7) << 3))];
                acc = MFMA32(af, qf[f], acc);
            }
            float p[16];
#pragma unroll
            for (int r = 0; r < 16; ++r)
                p[r] = (acc[r] >= tt) ? EXP2(acc[r]) : 0.f;
            unsigned c8[8];
#pragma unroll
            for (int i = 0; i < 8; ++i) c8[i] = cvtpk(p[2 * i], p[2 * i + 1]);
#pragma unroll
            for (int s = 0; s < 2; ++s) {
                unsigned a1 = c8[4 * s],     b1 = c8[4 * s + 2];
                unsigned a2 = c8[4 * s + 1], b2 = c8[4 * s + 3];
                asm("v_permlane32_swap_b32 %0, %1" : "+v"(a1), "+v"(b1));
                asm("v_permlane32_swap_b32 %0, %1" : "+v"(a2), "+v"(b2));
                u32x4 W = {a1, a2, b1, b2};
                bf16x8 pa = __builtin_bit_cast(bf16x8, W);
#pragma unroll
                for (int dt = 0; dt < 2; ++dt) {
                    int vrow = dt * 32 + ql;
                    int vcol = (kT * 32 + s * 16 + h * 8) ^ ((vrow & 7) << 3);
                    bf16x8 vf = *(bf16x8*)&vls[vrow * 64 + vcol];
                    oacc[dt] = MFMA32(pa, vf, oacc[dt]);
                }
            }
        }
        __syncthreads();
        if (c < 7) {
#pragma unroll
            for (int j = 0; j < 4; ++j) {
                int r = j * 16 + srow;
                *(bf16x8*)&skls[r * 64 + (scol ^ ((r & 7) << 3))] = sk[j];
                *(bf16x8*)&svls[r * 64 + (scol ^ ((r & 7) << 3))] = sv[j];
            }
            __syncthreads();
        }
    }

    if (kh == 1) {
#pragma unroll
        for (int dt = 0; dt < 2; ++dt)
#pragma unroll
            for (int r = 0; r < 16; ++r) {
                int crow = (r & 3) + 8 * (r >> 2) + 4 * h;
                comb[(rh * 32 + crow) * 65 + dt * 32 + ql] = oacc[dt][r];
            }
    }
    __syncthreads();
    if (kh == 1) return;
#pragma unroll
    for (int dt = 0; dt < 2; ++dt)
#pragma unroll
        for (int r = 0; r < 16; ++r) {
            int crow = (r & 3) + 8 * (r >> 2) + 4 * h;
            oacc[dt][r] += comb[(rh * 32 + crow) * 65 + dt * 32 + ql];
        }
#pragma unroll
    for (int dt = 0; dt < 2; ++dt)
#pragma unroll
        for (int r = 0; r < 16; r += 2) {
            int qr0 = qrow0 + (r & 3) + 8 * (r >> 2) + 4 * h;
            int qr1 = qrow0 + ((r + 1) & 3) + 8 * ((r + 1) >> 2) + 4 * h;
            unsigned w = cvtpk(oacc[dt][r], oacc[dt][r + 1]);
            *(unsigned short*)&aout[((size_t)b * SEQ + qr0) * CDIM + hh * 64 + dt * 32 + ql] =
                (unsigned short)w;
            *(unsigned short*)&aout[((size_t)b * SEQ + qr1) * CDIM + hh * 64 + dt * 32 + ql] =
                (unsigned short)(w >> 16);
        }
}

// ---------------------------------------------------------------------------
// Kernel 5: out = aoutb @ Wpt^T + b_proj + origin (MFMA, fp32 epilogue),
// T14 split staging.
// ---------------------------------------------------------------------------
__global__ __launch_bounds__(256) void proj_mfma(const short* __restrict__ A,
                                                 const short* __restrict__ Bt,
                                                 const float* __restrict__ bias,
                                                 const float* __restrict__ origin,
                                                 float* __restrict__ out) {
    const int K = 768, NN = 768;
    __shared__ short As[128 * 64];
    __shared__ short Bs[128 * 64];
    int tM = blockIdx.x * 128, tN = blockIdx.y * 128;
    int tid = threadIdx.x, wave = tid >> 6, lane = tid & 63, lg = lane >> 4, lc = lane & 15;
    int wr = wave >> 1, wc = wave & 1;
    int srow = tid >> 3, scol = (tid & 7) * 8;
    f32x4 acc[4][4] = {};

    bf16x8 sa[4], sb[4];
#pragma unroll
    for (int j = 0; j < 4; ++j) {
        int r = j * 32 + srow;
        sa[j] = *(const bf16x8*)&A[(size_t)(tM + r) * K + scol];
        sb[j] = *(const bf16x8*)&Bt[(size_t)(tN + r) * K + scol];
    }
#pragma unroll
    for (int j = 0; j < 4; ++j) {
        int r = j * 32 + srow;
        int sw = scol ^ ((r & 7) << 3);
        *(bf16x8*)&As[r * 64 + sw] = sa[j];
        *(bf16x8*)&Bs[r * 64 + sw] = sb[j];
    }
    __syncthreads();

    for (int kc = 0; kc < K; kc += 64) {
        if (kc + 64 < K) {
#pragma unroll
            for (int j = 0; j < 4; ++j) {
                int r = j * 32 + srow;
                sa[j] = *(const bf16x8*)&A[(size_t)(tM + r) * K + kc + 64 + scol];
                sb[j] = *(const bf16x8*)&Bt[(size_t)(tN + r) * K + kc + 64 + scol];
            }
        }
        bf16x8 af[4][2], bfr[4][2];
#pragma unroll
        for (int m4 = 0; m4 < 4; ++m4) {
            int r = wr * 64 + m4 * 16 + lc;
            int sw = (r & 7) << 3;
            af[m4][0] = *(bf16x8*)&As[r * 64 + ((lg * 8) ^ sw)];
            af[m4][1] = *(bf16x8*)&As[r * 64 + ((32 + lg * 8) ^ sw)];
        }
#pragma unroll
        for (int n4 = 0; n4 < 4; ++n4) {
            int r = wc * 64 + n4 * 16 + lc;
            int sw = (r & 7) << 3;
            bfr[n4][0] = *(bf16x8*)&Bs[r * 64 + ((lg * 8) ^ sw)];
            bfr[n4][1] = *(bf16x8*)&Bs[r * 64 + ((32 + lg * 8) ^ sw)];
        }
#pragma unroll
        for (int m4 = 0; m4 < 4; ++m4)
#pragma unroll
            for (int n4 = 0; n4 < 4; ++n4) {
                acc[m4][n4] = MFMA16(af[m4][0], bfr[n4][0], acc[m4][n4]);
                acc[m4][n4] = MFMA16(af[m4][1], bfr[n4][1], acc[m4][n4]);
            }
        __syncthreads();
        if (kc + 64 < K) {
#pragma unroll
            for (int j = 0; j < 4; ++j) {
                int r = j * 32 + srow;
                int sw = scol ^ ((r & 7) << 3);
                *(bf16x8*)&As[r * 64 + sw] = sa[j];
                *(bf16x8*)&Bs[r * 64 + sw] = sb[j];
            }
            __syncthreads();
        }
    }
#pragma unroll
    for (int m4 = 0; m4 < 4; ++m4)
#pragma unroll
        for (int n4 = 0; n4 < 4; ++n4)
#pragma unroll
            for (int r = 0; r < 4; ++r) {
                int row = tM + wr * 64 + m4 * 16 + lg * 4 + r;
                int col = tN + wc * 64 + n4 * 16 + lc;
                out[(size_t)row * NN + col] = acc[m4][n4][r] + bias[col] + origin[(size_t)row * NN + col];
            }
}

// ---------------------------------------------------------------------------
extern "C" void kernel_launch(void* const* d_in, const int* in_sizes, int n_in,
                              void* d_out, int out_size, void* d_ws, size_t ws_size,
                              hipStream_t stream) {
    const float* x      = (const float*)d_in[0];
    const float* origin = (const float*)d_in[1];
    const float* W_qkv  = (const float*)d_in[2];
    const float* W_proj = (const float*)d_in[3];
    const float* b_proj = (const float*)d_in[4];
    float* out = (float*)d_out;
    char* ws = (char*)d_ws;

    const size_t QKV_ELEMS = (size_t)BATCH * HEADS * SEQ * HD;   // 6291456
    const size_t X_ELEMS   = (size_t)BATCH * SEQ * CDIM;         // 6291456
    size_t off = 0;
    short* xb  = (short*)(ws + off); off += X_ELEMS * 2;
    short* wqt = (short*)(ws + off); off += (size_t)2304 * 768 * 2;
    short* wpt = (short*)(ws + off); off += (size_t)768 * 768 * 2;
    short* q   = (short*)(ws + off); off += QKV_ELEMS * 2;
    short* k   = (short*)(ws + off); off += QKV_ELEMS * 2;
    short* vt  = (short*)(ws + off); off += QKV_ELEMS * 2;
    short* aoutb = (short*)(ws + off); off += QKV_ELEMS * 2;
    float* orow = (float*)(ws + off); off += (size_t)BATCH * HEADS * SEQ * 4;
    unsigned* hist = (unsigned*)(ws + off); off += (size_t)BATCH * NB1 * 4;
    float* thr = (float*)(ws + off); off += 8 * 4;

    prep_all<<<dim3(3648), 256, 0, stream>>>(x, W_qkv, W_proj, xb, wqt, wpt, hist);
    qkv_mfma<<<dim3(64, 18), 256, 0, stream>>>(xb, wqt,
                                               (__hip_bfloat16*)q, (__hip_bfloat16*)k, (__hip_bfloat16*)vt);
    stats_mfma<<<dim3(BATCH * HEADS * 8), 256, 0, stream>>>(q, k, orow, hist);
    find_thr<<<dim3(BATCH), 256, 0, stream>>>(hist, thr);
    pv_mfma<<<dim3(BATCH * HEADS * 16), 256, 0, stream>>>(q, k, vt, orow, thr,
                                                          (__hip_bfloat16*)aoutb);
    proj_mfma<<<dim3(64, 6), 256, 0, stream>>>(aoutb, wpt, b_proj, origin, out);
}